// Round 20
// baseline (1882.234 us; speedup 1.0000x reference)
//
#include <hip/hip_runtime.h>
#include <cmath>
#include <cstddef>

#define NROWS 8192
#define HDIM  256
#define KNN   11
#define NT    64          // 8192/128 tile bands
#define TS    128
#define TILE_ELEMS (TS*TS)
#define NTILES (NT*(NT+1)/2)

enum { EPI_NONE=0, EPI_RELU=1, EPI_TANH=3, EPI_GATE=4, EPI_SDE=5 };
enum { NPE_NONE=0, NPE_RELU=1, NPE_RELU_BN=2 };

typedef __attribute__((ext_vector_type(2))) float v2f;

// ---- contraction-proof single-rounding f32 ops (np ufunc semantics) ----
__device__ __forceinline__ float add_rn(float a, float b){ float d; asm("v_add_f32 %0, %1, %2":"=v"(d):"v"(a),"v"(b)); return d; }
__device__ __forceinline__ float sub_rn(float a, float b){ float d; asm("v_sub_f32 %0, %1, %2":"=v"(d):"v"(a),"v"(b)); return d; }
__device__ __forceinline__ float mul_rn(float a, float b){ float d; asm("v_mul_f32 %0, %1, %2":"=v"(d):"v"(a),"v"(b)); return d; }

// ---- packed dual-f32 MULADD (np-bit-exact sim chain, proven R19) ----
__device__ __forceinline__ void pk_mac_lo(v2f &acc, v2f a2, v2f b2){
    v2f p;
    asm("v_pk_mul_f32 %0, %1, %2 op_sel:[0,0] op_sel_hi:[1,0]" : "=v"(p) : "v"(a2), "v"(b2));
    asm("v_pk_add_f32 %0, %1, %2" : "=v"(acc) : "v"(acc), "v"(p));
}
__device__ __forceinline__ void pk_mac_hi(v2f &acc, v2f a2, v2f b2){
    v2f p;
    asm("v_pk_mul_f32 %0, %1, %2 op_sel:[0,1] op_sel_hi:[1,1]" : "=v"(p) : "v"(a2), "v"(b2));
    asm("v_pk_add_f32 %0, %1, %2" : "=v"(acc) : "v"(acc), "v"(p));
}

// ---- packed dual FMA with src0 scalar broadcast (smooth path: SDE) ----
// lo-bcast: both lanes use a2.lo;  hi-bcast: both lanes use a2.hi.
__device__ __forceinline__ void pk_fma_blo(v2f &acc, v2f a2, v2f w2){
    asm("v_pk_fma_f32 %0, %1, %2, %0 op_sel:[0,0,0] op_sel_hi:[0,1,1]"
        : "+v"(acc) : "v"(a2), "v"(w2));
}
__device__ __forceinline__ void pk_fma_bhi(v2f &acc, v2f a2, v2f w2){
    asm("v_pk_fma_f32 %0, %1, %2, %0 op_sel:[1,0,0] op_sel_hi:[1,1,1]"
        : "+v"(acc) : "v"(a2), "v"(w2));
}

__device__ __host__ __forceinline__ size_t tidx(int br, int bc)
{   // row-major upper-triangle packing, br <= bc
    return (size_t)br * NT - (size_t)br * (br - 1) / 2 + (size_t)(bc - br);
}

__device__ __forceinline__ float epi_apply(int EPI, float z, int gn,
    const float* bias, const float* bn_m, const float* bn_r,
    const float* bn_g, const float* bn_b)
{
    if (EPI == NPE_NONE) return z;
    z = add_rn(z, bias[gn]);
    z = fmaxf(z, 0.f);
    if (EPI == NPE_RELU) return z;
    z = sub_rn(z, bn_m[gn]);
    z = mul_rn(z, bn_r[gn]);
    z = mul_rn(z, bn_g[gn]);
    z = add_rn(z, bn_b[gn]);
    return z;
}

// ======== MULADD-chain GEMM: 128x128 tile, 8x8/thread, k-major LDS (proven) ========
template<int EPI, bool TRANSB>
__global__ __launch_bounds__(256)
void gemm_ma2(const float* __restrict__ A, int lda,
              const float* __restrict__ B, int ldb,
              const float* __restrict__ bias,
              float* __restrict__ C, int ldc,
              int M, int N, int K,
              const float* __restrict__ bn_m, const float* __restrict__ bn_r,
              const float* __restrict__ bn_g, const float* __restrict__ bn_b)
{
    __shared__ float As[32][132];
    __shared__ float Bs[32][132];
    const int tid = threadIdx.x;
    const int tx = tid & 15, ty = tid >> 4;
    const int m0 = blockIdx.y * 128, n0 = blockIdx.x * 128;

    float acc[8][8];
    #pragma unroll
    for (int i = 0; i < 8; ++i)
        #pragma unroll
        for (int j = 0; j < 8; ++j) acc[i][j] = 0.f;

    for (int kc = 0; kc < K; kc += 32) {
        #pragma unroll
        for (int u = 0; u < 16; ++u) {
            int idx = tid + u * 256;
            int kk = idx & 31, m = idx >> 5;
            int gm = m0 + m, gk = kc + kk;
            As[kk][m] = (gm < M && gk < K) ? A[(size_t)gm * lda + gk] : 0.f;
        }
        #pragma unroll
        for (int u = 0; u < 16; ++u) {
            int idx = tid + u * 256;
            if (TRANSB) {
                int kk = idx & 31, n = idx >> 5;
                int gn = n0 + n, gk = kc + kk;
                Bs[kk][n] = (gn < N && gk < K) ? B[(size_t)gn * ldb + gk] : 0.f;
            } else {
                int n = idx & 127, kk = idx >> 7;
                int gn = n0 + n, gk = kc + kk;
                Bs[kk][n] = (gk < K && gn < N) ? B[(size_t)gk * ldb + gn] : 0.f;
            }
        }
        __syncthreads();
        #pragma unroll
        for (int kk = 0; kk < 32; ++kk) {
            float4 a0 = *(const float4*)&As[kk][ty * 8];
            float4 a1 = *(const float4*)&As[kk][ty * 8 + 4];
            float4 b0 = *(const float4*)&Bs[kk][tx * 8];
            float4 b1 = *(const float4*)&Bs[kk][tx * 8 + 4];
            float a[8] = {a0.x,a0.y,a0.z,a0.w,a1.x,a1.y,a1.z,a1.w};
            float b[8] = {b0.x,b0.y,b0.z,b0.w,b1.x,b1.y,b1.z,b1.w};
            #pragma unroll
            for (int i = 0; i < 8; ++i)
                #pragma unroll
                for (int j = 0; j < 8; ++j)
                    acc[i][j] = add_rn(acc[i][j], mul_rn(a[i], b[j]));
        }
        __syncthreads();
    }

    #pragma unroll
    for (int i = 0; i < 8; ++i) {
        int gm = m0 + ty * 8 + i;
        if (gm >= M) continue;
        #pragma unroll
        for (int j = 0; j < 8; ++j) {
            int gn = n0 + tx * 8 + j;
            if (gn >= N) continue;
            C[(size_t)gm * ldc + gn] = epi_apply(EPI, acc[i][j], gn, bias, bn_m, bn_r, bn_g, bn_b);
        }
    }
}

// ======== sym sim GEMM -> PACKED upper tiles; packed-f32 MULADD (proven R19) ========
__global__ __launch_bounds__(256)
void gemm_sim_sym_packed(const float* __restrict__ hn, float* __restrict__ P)
{
    size_t t = blockIdx.x;
    int br = 0;
    while ((size_t)(br + 1) * NT - (size_t)(br + 1) * br / 2 <= t) ++br;
    int bc = br + (int)(t - ((size_t)br * NT - (size_t)br * (br - 1) / 2));

    __shared__ float As[32][132];
    __shared__ float Bs[32][132];
    const int tid = threadIdx.x;
    const int tx = tid & 15, ty = tid >> 4;
    const int m0 = br * 128, n0 = bc * 128;

    v2f acc2[4][8];
    #pragma unroll
    for (int ip = 0; ip < 4; ++ip)
        #pragma unroll
        for (int j = 0; j < 8; ++j) { acc2[ip][j].x = 0.f; acc2[ip][j].y = 0.f; }

    #pragma unroll 1
    for (int kc = 0; kc < HDIM; kc += 32) {
        #pragma unroll
        for (int u = 0; u < 16; ++u) {
            int idx = tid + u * 256;
            int kk = idx & 31, m = idx >> 5;
            As[kk][m] = hn[(size_t)(m0 + m) * HDIM + kc + kk];
            Bs[kk][m] = hn[(size_t)(n0 + m) * HDIM + kc + kk];
        }
        __syncthreads();
        #pragma unroll
        for (int kk = 0; kk < 32; ++kk) {
            float4 a0 = *(const float4*)&As[kk][ty * 8];
            float4 a1 = *(const float4*)&As[kk][ty * 8 + 4];
            float4 b0 = *(const float4*)&Bs[kk][tx * 8];
            float4 b1 = *(const float4*)&Bs[kk][tx * 8 + 4];
            v2f a2[4], b2[4];
            a2[0].x = a0.x; a2[0].y = a0.y;  a2[1].x = a0.z; a2[1].y = a0.w;
            a2[2].x = a1.x; a2[2].y = a1.y;  a2[3].x = a1.z; a2[3].y = a1.w;
            b2[0].x = b0.x; b2[0].y = b0.y;  b2[1].x = b0.z; b2[1].y = b0.w;
            b2[2].x = b1.x; b2[2].y = b1.y;  b2[3].x = b1.z; b2[3].y = b1.w;
            #pragma unroll
            for (int ip = 0; ip < 4; ++ip)
                #pragma unroll
                for (int jp = 0; jp < 4; ++jp) {
                    pk_mac_lo(acc2[ip][2 * jp],     a2[ip], b2[jp]);
                    pk_mac_hi(acc2[ip][2 * jp + 1], a2[ip], b2[jp]);
                }
        }
        __syncthreads();
    }

    float* tile = P + t * TILE_ELEMS;
    #pragma unroll
    for (int ip = 0; ip < 4; ++ip) {
        float* tr0 = tile + (size_t)(ty * 8 + 2 * ip) * TS + tx * 8;
        float* tr1 = tile + (size_t)(ty * 8 + 2 * ip + 1) * TS + tx * 8;
        #pragma unroll
        for (int j = 0; j < 8; ++j) {
            tr0[j] = acc2[ip][j].x;
            tr1[j] = acc2[ip][j].y;
        }
    }
}

// ---- BN reciprocal-sqrt ----
__global__ void bn_prep_np(const float* __restrict__ v, float* __restrict__ r)
{
    int i = threadIdx.x;
    float vpe = add_rn(v[i], 1e-5f);
    r[i] = 1.0f / sqrtf(vpe);
}

// ---- numpy scalar-pairwise row L2-normalize ----
__global__ __launch_bounds__(256)
void rownorm_np2(const float* __restrict__ h, float* __restrict__ hn)
{
    int r = blockIdx.x * 256 + threadIdx.x;
    if (r >= NROWS) return;
    const float* x = h + (size_t)r * HDIM;
    float tot = 0.f;
    #pragma unroll
    for (int half = 0; half < 2; ++half) {
        const float* a = x + half * 128;
        float rr[8];
        #pragma unroll
        for (int jj = 0; jj < 8; ++jj) rr[jj] = mul_rn(a[jj], a[jj]);
        #pragma unroll 1
        for (int ii = 8; ii < 128; ii += 8) {
            #pragma unroll
            for (int jj = 0; jj < 8; ++jj) rr[jj] = add_rn(rr[jj], mul_rn(a[ii + jj], a[ii + jj]));
        }
        float blk = add_rn(add_rn(add_rn(rr[0], rr[1]), add_rn(rr[2], rr[3])),
                           add_rn(add_rn(rr[4], rr[5]), add_rn(rr[6], rr[7])));
        tot = (half == 0) ? blk : add_rn(tot, blk);
    }
    float den = fmaxf(sqrtf(tot), 1e-12f);
    float* o = hn + (size_t)r * HDIM;
    for (int ii = 0; ii < HDIM; ++ii) o[ii] = x[ii] / den;
}

// ---- guarded sorted-insert (exact: under strict >, v <= current min never enters) ----
__device__ __forceinline__ void ins11(float (&av)[KNN], int (&ai)[KNN], float v, int vi)
{
    if (v > av[KNN - 1]) {
        #pragma unroll
        for (int j = 0; j < KNN; ++j) {
            bool better = (v > av[j]);
            float tv = better ? av[j] : v;  int ti = better ? ai[j] : vi;
            av[j] = better ? v : av[j];     ai[j] = better ? vi : ai[j];
            v = tv; vi = ti;
        }
    }
}

// ======== wave-per-row top-11 over PACKED tiles; mirror via block LDS staging (proven) ========
__global__ __launch_bounds__(256)
void topk_wave_sym(const float* __restrict__ P,
                   int* __restrict__ idx_out, float* __restrict__ wgt_out)
{
    __shared__ float colbuf[4][132];
    const int tid = threadIdx.x;
    const int w = tid >> 6;
    const int lane = tid & 63;
    const int wid0 = blockIdx.x * 4;
    const int wid = wid0 + w;
    const int br = wid >> 7, rr = wid & 127;
    const int rr0 = wid0 & 127;          // multiple of 4; all 4 rows in same band

    float av[KNN]; int ai[KNN];
    #pragma unroll
    for (int j = 0; j < KNN; ++j) { av[j] = -3.402823e38f; ai[j] = 0x7fffffff; }

    #pragma unroll 1
    for (int cb = 0; cb < NT; ++cb) {
        int c0 = cb * TS + lane * 2;
        if (cb >= br) {
            const float* tile = P + tidx(br, cb) * TILE_ELEMS;
            float2 v2 = *(const float2*)&tile[(size_t)rr * TS + lane * 2];
            ins11(av, ai, v2.x, c0);
            ins11(av, ai, v2.y, c0 + 1);
        } else {
            const float* tile = P + tidx(cb, br) * TILE_ELEMS;
            __syncthreads();
            if (tid < 128) {
                float4 v4 = *(const float4*)&tile[(size_t)tid * TS + rr0];
                colbuf[0][tid] = v4.x; colbuf[1][tid] = v4.y;
                colbuf[2][tid] = v4.z; colbuf[3][tid] = v4.w;
            }
            __syncthreads();
            float va = colbuf[w][lane * 2];
            float vb = colbuf[w][lane * 2 + 1];
            ins11(av, ai, va, c0);
            ins11(av, ai, vb, c0 + 1);
        }
    }

    // butterfly merge across 64 lanes; comparator (v desc, idx asc)
    #pragma unroll 1
    for (int m = 1; m < 64; m <<= 1) {
        float bv[KNN]; int bi[KNN];
        #pragma unroll
        for (int j = 0; j < KNN; ++j) {
            bv[j] = __shfl_xor(av[j], m, 64);
            bi[j] = __shfl_xor(ai[j], m, 64);
        }
        #pragma unroll
        for (int j = 0; j < KNN; ++j) {
            float v = bv[j]; int vi = bi[j];
            bool enter = (v > av[KNN - 1]) || (v == av[KNN - 1] && vi < ai[KNN - 1]);
            if (enter) {
                #pragma unroll
                for (int q = 0; q < KNN; ++q) {
                    bool better = (v > av[q]) || (v == av[q] && vi < ai[q]);
                    float tv = better ? av[q] : v;  int ti = better ? ai[q] : vi;
                    av[q] = better ? v : av[q];     ai[q] = better ? vi : ai[q];
                    v = tv; vi = ti;
                }
            }
        }
    }

    if (lane == 0) {
        double s = 0.0;
        #pragma unroll
        for (int j = 0; j < KNN; ++j) s += (double)av[j];
        double den = fmax(s, 1.0);
        #pragma unroll
        for (int j = 0; j < KNN; ++j) {
            idx_out[(size_t)wid * KNN + j] = ai[j];
            wgt_out[(size_t)wid * KNN + j] = (float)((double)av[j] / den);
        }
    }
}

// ======== full-row top-11 (chunked fallback path, proven) ========
__global__ __launch_bounds__(256)
void topk_wave(const float* __restrict__ sim, int r0, int R,
               int* __restrict__ idx_out, float* __restrict__ wgt_out)
{
    const int wid = blockIdx.x * 4 + (threadIdx.x >> 6);
    const int lane = threadIdx.x & 63;
    if (wid >= R) return;
    const float* row = sim + (size_t)wid * NROWS;

    float av[KNN]; int ai[KNN];
    #pragma unroll
    for (int j = 0; j < KNN; ++j) { av[j] = -3.402823e38f; ai[j] = 0x7fffffff; }

    #pragma unroll 1
    for (int it = 0; it < NROWS / 256; ++it) {
        float4 v4 = *(const float4*)&row[lane * 4 + it * 256];
        float vv[4] = {v4.x, v4.y, v4.z, v4.w};
        #pragma unroll
        for (int q = 0; q < 4; ++q)
            ins11(av, ai, vv[q], lane * 4 + it * 256 + q);
    }

    #pragma unroll 1
    for (int m = 1; m < 64; m <<= 1) {
        float bv[KNN]; int bi[KNN];
        #pragma unroll
        for (int j = 0; j < KNN; ++j) {
            bv[j] = __shfl_xor(av[j], m, 64);
            bi[j] = __shfl_xor(ai[j], m, 64);
        }
        #pragma unroll
        for (int j = 0; j < KNN; ++j) {
            float v = bv[j]; int vi = bi[j];
            bool enter = (v > av[KNN - 1]) || (v == av[KNN - 1] && vi < ai[KNN - 1]);
            if (enter) {
                #pragma unroll
                for (int q = 0; q < KNN; ++q) {
                    bool better = (v > av[q]) || (v == av[q] && vi < ai[q]);
                    float tv = better ? av[q] : v;  int ti = better ? ai[q] : vi;
                    av[q] = better ? v : av[q];     ai[q] = better ? vi : ai[q];
                    v = tv; vi = ti;
                }
            }
        }
    }

    if (lane == 0) {
        double s = 0.0;
        #pragma unroll
        for (int j = 0; j < KNN; ++j) s += (double)av[j];
        double den = fmax(s, 1.0);
        int gr = r0 + wid;
        #pragma unroll
        for (int j = 0; j < KNN; ++j) {
            idx_out[(size_t)gr * KNN + j] = ai[j];
            wgt_out[(size_t)gr * KNN + j] = (float)((double)av[j] / den);
        }
    }
}

// ================= fused SDE with packed-f32 FMA (smooth path) =================
#define SROWS 16
#define SSTR  (HDIM + 4)

__device__ __forceinline__ void sde_layer(
    const float (*in)[SSTR], float (*out)[SSTR],
    const float* __restrict__ W, const float* __restrict__ bias,
    const float* __restrict__ tw, float t, int rg, int cg)
{
    __syncthreads();
    v2f acc2[4][2];          // [row i][col pair jp]; cols cg*4 + jp*2 + {0,1}
    #pragma unroll
    for (int i = 0; i < 4; ++i)
        #pragma unroll
        for (int jp = 0; jp < 2; ++jp) { acc2[i][jp].x = 0.f; acc2[i][jp].y = 0.f; }

    #pragma unroll 1
    for (int k = 0; k < HDIM; k += 4) {
        float4 a4[4];
        #pragma unroll
        for (int i = 0; i < 4; ++i) a4[i] = *(const float4*)&in[rg * 4 + i][k];
        float4 w4[4];
        #pragma unroll
        for (int q = 0; q < 4; ++q) w4[q] = *(const float4*)&W[(size_t)(k + q) * HDIM + cg * 4];
        #pragma unroll
        for (int i = 0; i < 4; ++i) {
            v2f a01, a23;
            a01.x = a4[i].x; a01.y = a4[i].y;
            a23.x = a4[i].z; a23.y = a4[i].w;
            #pragma unroll
            for (int q = 0; q < 4; ++q) {
                v2f wlo, whi;
                wlo.x = w4[q].x; wlo.y = w4[q].y;
                whi.x = w4[q].z; whi.y = w4[q].w;
                if (q == 0)      { pk_fma_blo(acc2[i][0], a01, wlo); pk_fma_blo(acc2[i][1], a01, whi); }
                else if (q == 1) { pk_fma_bhi(acc2[i][0], a01, wlo); pk_fma_bhi(acc2[i][1], a01, whi); }
                else if (q == 2) { pk_fma_blo(acc2[i][0], a23, wlo); pk_fma_blo(acc2[i][1], a23, whi); }
                else             { pk_fma_bhi(acc2[i][0], a23, wlo); pk_fma_bhi(acc2[i][1], a23, whi); }
            }
        }
    }

    float bb[4];
    #pragma unroll
    for (int j = 0; j < 4; ++j) {
        bb[j] = bias[cg * 4 + j];
        if (tw) bb[j] += t * tw[cg * 4 + j];
    }
    #pragma unroll
    for (int i = 0; i < 4; ++i) {
        out[rg * 4 + i][cg * 4 + 0] = tanhf(acc2[i][0].x + bb[0]);
        out[rg * 4 + i][cg * 4 + 1] = tanhf(acc2[i][0].y + bb[1]);
        out[rg * 4 + i][cg * 4 + 2] = tanhf(acc2[i][1].x + bb[2]);
        out[rg * 4 + i][cg * 4 + 3] = tanhf(acc2[i][1].y + bb[3]);
    }
}

__global__ __launch_bounds__(256)
void sde_fused(const float* __restrict__ w1, const float* __restrict__ b1,
               const float* __restrict__ w2, const float* __restrict__ b2,
               const float* __restrict__ w3, const float* __restrict__ b3,
               float* __restrict__ h)
{
    __shared__ float hs[SROWS][SSTR];
    __shared__ float bufA[SROWS][SSTR];
    __shared__ float bufB[SROWS][SSTR];
    const int tid = threadIdx.x;
    const int r0 = blockIdx.x * SROWS;
    const int rg = tid >> 6;
    const int cg = tid & 63;

    for (int i = tid; i < SROWS * HDIM; i += 256) {
        int r = i >> 8, c = i & 255;
        hs[r][c] = h[(size_t)(r0 + r) * HDIM + c];
    }

    #pragma unroll 1
    for (int s = 0; s < 10; ++s) {
        float t = 0.1f * (float)s;
        sde_layer(hs,  bufA, w1, b1, w1 + (size_t)HDIM * HDIM, t, rg, cg);
        sde_layer(bufA, bufB, w2, b2, nullptr, 0.f, rg, cg);
        sde_layer(bufB, bufA, w3, b3, nullptr, 0.f, rg, cg);
        __syncthreads();
        for (int i = tid; i < SROWS * HDIM; i += 256) {
            int r = i >> 8, c = i & 255;
            hs[r][c] += 0.1f * bufA[r][c];
        }
    }
    __syncthreads();
    for (int i = tid; i < SROWS * HDIM; i += 256) {
        int r = i >> 8, c = i & 255;
        h[(size_t)(r0 + r) * HDIM + c] = hs[r][c];
    }
}

// ================= downstream 64-tile GEMM (proven) =================
template<int EPI, bool TRANSB>
__global__ __launch_bounds__(256)
void gemm_f32(const float* __restrict__ A, int lda,
              const float* __restrict__ B, int ldb,
              const float* __restrict__ bias, const float* __restrict__ bias2, float bcoef,
              float* __restrict__ C, int ldc,
              int M, int N, int K,
              const float* __restrict__ E1, const float* __restrict__ E2, float coef)
{
    __shared__ float As[16][64];
    __shared__ float Bs[16][64];
    const int tid = threadIdx.x;
    const int tx = tid & 15, ty = tid >> 4;
    const int m0 = blockIdx.y * 64, n0 = blockIdx.x * 64;

    float acc[4][4] = {{0.f}};

    for (int k0 = 0; k0 < K; k0 += 16) {
        #pragma unroll
        for (int u = 0; u < 4; ++u) {
            int i = tid + u * 256;
            int kk = i & 15, m = i >> 4;
            int gm = m0 + m, gk = k0 + kk;
            As[kk][m] = (gm < M && gk < K) ? A[(size_t)gm * lda + gk] : 0.f;
        }
        if (!TRANSB) {
            #pragma unroll
            for (int u = 0; u < 4; ++u) {
                int i = tid + u * 256;
                int n = i & 63, kk = i >> 6;
                int gk = k0 + kk, gn = n0 + n;
                Bs[kk][n] = (gk < K && gn < N) ? B[(size_t)gk * ldb + gn] : 0.f;
            }
        } else {
            #pragma unroll
            for (int u = 0; u < 4; ++u) {
                int i = tid + u * 256;
                int kk = i & 15, n = i >> 4;
                int gk = k0 + kk, gn = n0 + n;
                Bs[kk][n] = (gk < K && gn < N) ? B[(size_t)gn * ldb + gk] : 0.f;
            }
        }
        __syncthreads();
        #pragma unroll
        for (int kk = 0; kk < 16; ++kk) {
            float4 avv = *(const float4*)&As[kk][ty * 4];
            float4 bvv = *(const float4*)&Bs[kk][tx * 4];
            float a[4] = {avv.x, avv.y, avv.z, avv.w};
            float b[4] = {bvv.x, bvv.y, bvv.z, bvv.w};
            #pragma unroll
            for (int i2 = 0; i2 < 4; ++i2)
                #pragma unroll
                for (int j = 0; j < 4; ++j)
                    acc[i2][j] += a[i2] * b[j];
        }
        __syncthreads();
    }

    #pragma unroll
    for (int i2 = 0; i2 < 4; ++i2) {
        int gm = m0 + ty * 4 + i2;
        if (gm >= M) continue;
        #pragma unroll
        for (int j = 0; j < 4; ++j) {
            int gn = n0 + tx * 4 + j;
            if (gn >= N) continue;
            float z = acc[i2][j];
            if (bias)  z += bias[gn];
            if (bias2) z += bcoef * bias2[gn];
            float r;
            if constexpr (EPI == EPI_NONE) {
                r = z;
            } else if constexpr (EPI == EPI_RELU) {
                r = fmaxf(z, 0.f);
            } else if constexpr (EPI == EPI_TANH) {
                r = tanhf(z);
            } else if constexpr (EPI == EPI_GATE) {
                float g = 1.f / (1.f + expf(-z));
                float avv = E1[(size_t)gm * ldc + gn];
                float hvv = E2[(size_t)gm * ldc + gn];
                r = fmaxf(g * avv + (1.f - g) * hvv, 0.f);
            } else {
                r = E1[(size_t)gm * ldc + gn] + tanhf(z) * coef;
            }
            C[(size_t)gm * ldc + gn] = r;
        }
    }
}

__global__ __launch_bounds__(256)
void gather_agg(const float* __restrict__ ht, const int* __restrict__ idx,
                const float* __restrict__ wgt, float* __restrict__ agg)
{
    int r = blockIdx.x, tid = threadIdx.x;
    __shared__ int   si[KNN];
    __shared__ float sw[KNN];
    if (tid < KNN) { si[tid] = idx[(size_t)r * KNN + tid]; sw[tid] = wgt[(size_t)r * KNN + tid]; }
    __syncthreads();
    float acc = 0.f;
    #pragma unroll
    for (int j = 0; j < KNN; ++j) acc += sw[j] * ht[(size_t)si[j] * HDIM + tid];
    agg[(size_t)r * HDIM + tid] = acc;
}

__global__ __launch_bounds__(256)
void te_gbias(const float* __restrict__ w1, const float* __restrict__ b1,
              const float* __restrict__ w2, const float* __restrict__ b2,
              const float* __restrict__ gw, const float* __restrict__ gb,
              float t, float* __restrict__ gbias)
{
    __shared__ float hid[16];
    __shared__ float te[256];
    int tid = threadIdx.x;
    if (tid < 16) hid[tid] = fmaxf(t * w1[tid] + b1[tid], 0.f);
    __syncthreads();
    float acc = b2[tid];
    #pragma unroll
    for (int i = 0; i < 16; ++i) acc += hid[i] * w2[i * 256 + tid];
    te[tid] = acc;
    __syncthreads();
    float g = gb[tid];
    for (int j = 0; j < 256; ++j) g += te[j] * gw[j * 256 + tid];
    gbias[tid] = g;
}

extern "C" void kernel_launch(void* const* d_in, const int* in_sizes, int n_in,
                              void* d_out, int out_size, void* d_ws, size_t ws_size,
                              hipStream_t stream)
{
    (void)in_sizes; (void)n_in; (void)out_size;
    const float* x       = (const float*)d_in[0];
    const float* enc_w1  = (const float*)d_in[1];
    const float* enc_b1  = (const float*)d_in[2];
    const float* enc_w2  = (const float*)d_in[3];
    const float* enc_b2  = (const float*)d_in[4];
    const float* bn_g    = (const float*)d_in[5];
    const float* bn_b    = (const float*)d_in[6];
    const float* bn_m    = (const float*)d_in[7];
    const float* bn_v    = (const float*)d_in[8];
    const float* tg_node_w = (const float*)d_in[9];
    const float* tg_node_b = (const float*)d_in[10];
    const float* tg_t_w1 = (const float*)d_in[11];
    const float* tg_t_b1 = (const float*)d_in[12];
    const float* tg_t_w2 = (const float*)d_in[13];
    const float* tg_t_b2 = (const float*)d_in[14];
    const float* tg_gate_w = (const float*)d_in[15];
    const float* tg_gate_b = (const float*)d_in[16];
    const float* sde_w1  = (const float*)d_in[17];
    const float* sde_b1  = (const float*)d_in[18];
    const float* sde_w2  = (const float*)d_in[19];
    const float* sde_b2  = (const float*)d_in[20];
    const float* sde_w3  = (const float*)d_in[21];
    const float* sde_b3  = (const float*)d_in[22];
    const float* dec_w1  = (const float*)d_in[23];
    const float* dec_b1  = (const float*)d_in[24];
    const float* dec_w2  = (const float*)d_in[25];
    const float* dec_b2  = (const float*)d_in[26];
    float* out = (float*)d_out;

    const size_t NH = (size_t)NROWS * HDIM;
    const size_t NK = (size_t)NROWS * KNN;
    const size_t PACKED_BYTES = (size_t)NTILES * TILE_ELEMS * 4;  // 136.3 MB

    char* p = (char*)d_ws;
    float* h    = (float*)p;  p += NH * 4;
    float* hn   = (float*)p;  p += NH * 4;
    float* t1   = (float*)p;  p += NH * 4;
    float* t2   = (float*)p;  p += NH * 4;
    int*   ki   = (int*)p;    p += NK * 4;
    float* kw   = (float*)p;  p += NK * 4;
    float* bn_r   = (float*)p; p += 256 * 4;
    float* gbias  = (float*)p; p += 256 * 4;
    p += (16 - ((uintptr_t)p & 15)) & 15;
    float* simw = (float*)p;   // packed tiles OR chunked sim rows

    size_t used_bytes = (size_t)(p - (char*)d_ws);
    size_t availB = (ws_size > used_bytes) ? ws_size - used_bytes : 0;
    bool packed = (availB >= PACKED_BYTES);

    int chunk = 128;
    if (!packed) {
        long long avail2 = (long long)availB;
        chunk = (avail2 > 0) ? (int)(avail2 / ((long long)NROWS * 4)) : 128;
        if (chunk > NROWS) chunk = NROWS;
        chunk &= ~127;
        if (chunk < 128) chunk = 128;
    }

    dim3 blk(256);
    dim3 g64(4, NROWS / 64);
    dim3 g128(2, NROWS / 128);

    bn_prep_np<<<1, 256, 0, stream>>>(bn_v, bn_r);

    // ---- np-matching MULADD chain: encoder -> norm -> sim -> top-11
    gemm_ma2<NPE_RELU, false><<<g128, blk, 0, stream>>>(
        x, 83, enc_w1, 256, enc_b1, t1, 256, NROWS, 256, 83, nullptr, nullptr, nullptr, nullptr);
    gemm_ma2<NPE_RELU_BN, false><<<g128, blk, 0, stream>>>(
        t1, 256, enc_w2, 256, enc_b2, h, 256, NROWS, 256, 256, bn_m, bn_r, bn_g, bn_b);
    rownorm_np2<<<NROWS / 256, 256, 0, stream>>>(h, hn);

    if (packed) {
        gemm_sim_sym_packed<<<NTILES, blk, 0, stream>>>(hn, simw);
        topk_wave_sym<<<NROWS / 4, 256, 0, stream>>>(simw, ki, kw);
    } else {
        for (int r0 = 0; r0 < NROWS; r0 += chunk) {
            int R = NROWS - r0; if (R > chunk) R = chunk;
            gemm_ma2<NPE_NONE, true><<<dim3(NROWS / 128, (R + 127) / 128), blk, 0, stream>>>(
                hn + (size_t)r0 * HDIM, HDIM, hn, HDIM, nullptr,
                simw, NROWS, R, NROWS, HDIM, nullptr, nullptr, nullptr, nullptr);
            topk_wave<<<(R + 3) / 4, 256, 0, stream>>>(simw, r0, R, ki, kw);
        }
    }

    // ---- temporal gated graph conv layers (proven 64-tile fp32)
    float tval = 0.f;
    for (int l = 0; l < 2; ++l) {
        te_gbias<<<1, 256, 0, stream>>>(
            tg_t_w1 + l * 16, tg_t_b1 + l * 16,
            tg_t_w2 + (size_t)l * 16 * 256, tg_t_b2 + l * 256,
            tg_gate_w + ((size_t)l * 512 + 256) * 256, tg_gate_b + l * 256,
            tval, gbias);
        gemm_f32<EPI_NONE, false><<<g64, blk, 0, stream>>>(
            h, 256, tg_node_w + (size_t)l * 256 * 256, 256,
            tg_node_b + l * 256, nullptr, 0.f, t1, 256, NROWS, 256, 256,
            nullptr, nullptr, 0.f);
        gather_agg<<<NROWS, 256, 0, stream>>>(t1, ki, kw, t2);
        gemm_f32<EPI_GATE, false><<<g64, blk, 0, stream>>>(
            t2, 256, tg_gate_w + (size_t)l * 512 * 256, 256,
            gbias, nullptr, 0.f, h, 256, NROWS, 256, 256,
            t2, t1, 0.f);
        tval += 0.5f;
    }

    // ---- fused SDE (packed-f32 FMA)
    sde_fused<<<NROWS / SROWS, 256, 0, stream>>>(
        sde_w1, sde_b1, sde_w2, sde_b2, sde_w3, sde_b3, h);

    // ---- decoder
    gemm_f32<EPI_RELU, false><<<dim3(2, NROWS / 64), blk, 0, stream>>>(
        h, 256, dec_w1, 128, dec_b1, nullptr, 0.f, t1, 128, NROWS, 128, 256,
        nullptr, nullptr, 0.f);
    gemm_f32<EPI_NONE, false><<<dim3(1, NROWS / 64), blk, 0, stream>>>(
        t1, 128, dec_w2, 34, dec_b2, nullptr, 0.f, out, 34, NROWS, 34, 128,
        nullptr, nullptr, 0.f);
}